// Round 2
// baseline (375.657 us; speedup 1.0000x reference)
//
#include <hip/hip_runtime.h>

#define NN 50000
#define EE 800000
#define DD 512
#define HH 8
#define BA 160            // binning blocks (CHUNK = EE/BA exactly)
#define CHUNK 5000
#define NBIN 196          // coarse bins: dst >> 8
#define BCAP 4608         // per-bin edge capacity (mean 4096, sd 64; P(exceed) ~ 1e-13)
#define GBLK 782          // gemm1 tile blocks (4 tiles each)
#define NTILE 3125        // NN/16 exact
#define AGBLK 1563        // ceil(NN*8/256)
#define GOFF 256          // mega: blocks >= GOFF run the gemm path
#define CSRB 256          // mega: blocks < CSRB participate in global barriers

typedef short bf16x8 __attribute__((ext_vector_type(8)));
typedef float f32x4 __attribute__((ext_vector_type(4)));

union U16 { uint4 u; bf16x8 v; unsigned short h[8]; };

__device__ __forceinline__ unsigned short f2bf(float f) {
    union { float f; unsigned int i; } c; c.f = f;
    unsigned int i = c.i;
    i += 0x7fffu + ((i >> 16) & 1u);   // RNE
    return (unsigned short)(i >> 16);
}

// Device-scope barrier over the CSRB barrier-blocks. One counter per instance
// (zeroed by a memset graph node) -> no generation/reset logic needed.
// Safe vs dispatch order: non-participating (gemm) blocks never wait, always
// retire, so the 256 participants always become co-resident (40KB LDS -> up
// to 4/CU; 256 blocks <= capacity).
__device__ __forceinline__ void gbar(int* c) {
    __syncthreads();
    if (threadIdx.x == 0) {
        __hip_atomic_fetch_add(c, 1, __ATOMIC_ACQ_REL, __HIP_MEMORY_SCOPE_AGENT);
        while (__hip_atomic_load(c, __ATOMIC_ACQUIRE, __HIP_MEMORY_SCOPE_AGENT) < CSRB)
            __builtin_amdgcn_s_sleep(1);
    }
    __syncthreads();
}

// ===== MEGA: gemm1 (blocks GOFF..) || full CSR build (blocks 0..CSRB-1) ======
__global__ __launch_bounds__(256) void k_mega(const float4* __restrict__ x4,
                                              const float* __restrict__ W1,
                                              const int* __restrict__ eidx,
                                              float* __restrict__ t1,
                                              int* __restrict__ blockhist,
                                              int* __restrict__ binTotal,
                                              int* __restrict__ binBase,
                                              int* __restrict__ bucket,
                                              int* __restrict__ row,
                                              int* __restrict__ adj,
                                              float* __restrict__ dinvA,
                                              int* __restrict__ bar) {
    __shared__ int smem[2 * BCAP + 768];              // 39.9 KB (build needs it)
    int t = threadIdx.x;
    int b = blockIdx.x;
    const int* dst = eidx + EE;

    if (b >= GOFF) {
        // ---------------- gemm1 path (no barriers) ----------------
        unsigned short* sbf = (unsigned short*)smem;  // first 16 KB
        for (int i = t; i < 16 * 64 * 8; i += 256) {
            int lane = (i >> 3) & 63, j = i & 7;
            int n = lane & 15;
            int k = (i >> 9) * 32 + ((lane >> 4) * 8) + j;
            sbf[i] = (n < HH) ? f2bf(W1[k * HH + n]) : (unsigned short)0;
        }
        __syncthreads();
        int wave = t >> 6, lane = t & 63;
        int tile = (b - GOFF) * 4 + wave;
        if (tile >= NTILE) return;
        int node0 = tile * 16;
        int m = lane & 15, q = lane >> 4;
        const float4* xrow = x4 + (size_t)(node0 + m) * (DD / 4) + q * 2;
        const uint4* bfrag = (const uint4*)sbf;
        f32x4 acc = {0.f, 0.f, 0.f, 0.f};

        float4 bufA[8], bufB[8];
#define LOADG(buf, g)                                                      \
    _Pragma("unroll")                                                      \
    for (int s = 0; s < 4; ++s) {                                          \
        buf[2 * s]     = xrow[((g) * 4 + s) * 8];                          \
        buf[2 * s + 1] = xrow[((g) * 4 + s) * 8 + 1];                      \
    }
#define MFMAG(buf, g)                                                      \
    _Pragma("unroll")                                                      \
    for (int s = 0; s < 4; ++s) {                                          \
        U16 a, bb;                                                         \
        float4 u0 = buf[2 * s], u1 = buf[2 * s + 1];                       \
        a.h[0] = f2bf(u0.x); a.h[1] = f2bf(u0.y);                          \
        a.h[2] = f2bf(u0.z); a.h[3] = f2bf(u0.w);                          \
        a.h[4] = f2bf(u1.x); a.h[5] = f2bf(u1.y);                          \
        a.h[6] = f2bf(u1.z); a.h[7] = f2bf(u1.w);                          \
        bb.u = bfrag[((g) * 4 + s) * 64 + lane];                           \
        acc = __builtin_amdgcn_mfma_f32_16x16x32_bf16(a.v, bb.v, acc, 0, 0, 0); \
    }
        LOADG(bufA, 0)
        LOADG(bufB, 1)
        MFMAG(bufA, 0)
        LOADG(bufA, 2)
        MFMAG(bufB, 1)
        LOADG(bufB, 3)
        MFMAG(bufA, 2)
        MFMAG(bufB, 3)
#undef LOADG
#undef MFMAG
        if (m < HH) {                                  // C: col=lane&15, row=q*4+r
            int base = (node0 + q * 4) * HH + m;
            t1[base]          = acc[0];
            t1[base + HH]     = acc[1];
            t1[base + 2 * HH] = acc[2];
            t1[base + 3 * HH] = acc[3];
        }
        return;
    }

    // ---------------- CSR path: 5 phases over CSRB barrier-blocks ----------
    // phase 0: per-chunk histogram (blocks 0..BA-1)
    if (b < BA) {
        int* h = smem;
        h[t] = 0; __syncthreads();
        int base = b * CHUNK;
#pragma unroll
        for (int it = 0; it < 20; ++it) {
            int i = it * 256 + t;
            if (i < CHUNK) atomicAdd(&h[dst[base + i] >> 8], 1);
        }
        __syncthreads();
        blockhist[b * 256 + t] = h[t];
    }
    gbar(bar + 0);

    // phase 1: per-bin column scan over the BA chunk counts (in-place)
    {
        int* s = smem;
        int v = (t < BA) ? blockhist[t * 256 + b] : 0;
        s[t] = v; __syncthreads();
        for (int off = 1; off < 256; off <<= 1) {
            int x = (t >= off) ? s[t - off] : 0;
            __syncthreads();
            if (t >= off) s[t] += x;
            __syncthreads();
        }
        if (t < BA) blockhist[t * 256 + b] = s[t] - v;  // chunk-local exclusive
        if (t == 255) binTotal[b] = s[255];
    }
    gbar(bar + 1);

    // phase 2: cross-bin scan -> binBase (block 0 only)
    if (b == 0) {
        int* s = smem;
        int v = binTotal[t];
        s[t] = v; __syncthreads();
        for (int off = 1; off < 256; off <<= 1) {
            int x = (t >= off) ? s[t - off] : 0;
            __syncthreads();
            if (t >= off) s[t] += x;
            __syncthreads();
        }
        binBase[t] = s[t] - v;
        if (t == 255) { binBase[256] = s[255]; row[NN] = s[255]; }
    }
    gbar(bar + 2);

    // phase 3: scatter edges into coarse buckets (blocks 0..BA-1)
    if (b < BA) {
        int* cur = smem;
        cur[t] = binBase[t] + blockhist[b * 256 + t];
        __syncthreads();
        int base = b * CHUNK;
#pragma unroll
        for (int it = 0; it < 20; ++it) {
            int i = it * 256 + t;
            if (i < CHUNK) {
                int s_ = eidx[base + i], d = eidx[EE + base + i];
                int pos = atomicAdd(&cur[d >> 8], 1);
                bucket[pos] = (s_ << 8) | (d & 255);
            }
        }
    }
    gbar(bar + 3);

    // phase 4: build CSR per bin (LDS counting sort) (blocks 0..NBIN-1)
    if (b < NBIN) {
        int bin = b;
        int n0 = bin << 8;
        int segStart = binBase[bin];
        int count = binBase[bin + 1] - segStart;
        if (count > BCAP) count = BCAP;               // p ~ 0 guard
        int* lds_in  = smem;                          // packed entries
        int* lds_out = smem + BCAP;
        int* cnt     = smem + 2 * BCAP;
        int* off     = smem + 2 * BCAP + 256;
        int* cur2    = smem + 2 * BCAP + 512;
        cnt[t] = 0; __syncthreads();
        for (int i = t; i < count; i += 256) {
            int p = bucket[segStart + i];
            lds_in[i] = p;
            atomicAdd(&cnt[p & 255], 1);
        }
        __syncthreads();
        off[t] = cnt[t]; __syncthreads();
        for (int o = 1; o < 256; o <<= 1) {
            int x = (t >= o) ? off[t - o] : 0;
            __syncthreads();
            if (t >= o) off[t] += x;
            __syncthreads();
        }
        int excl = off[t] - cnt[t];
        cur2[t] = excl;
        int n = n0 + t;
        if (n < NN) {
            row[n] = segStart + excl;
            dinvA[n] = rsqrtf((float)cnt[t] + 1.0f);
        }
        __syncthreads();
        for (int i = t; i < count; i += 256) {
            int p = lds_in[i];
            int pos = atomicAdd(&cur2[p & 255], 1);
            lds_out[pos] = p >> 8;                    // src
        }
        __syncthreads();
        for (int i = t; i < count; i += 256)
            adj[segStart + i] = lds_out[i];           // coalesced stream-out
    }
}

// ===== K5: agg1 + bias + LayerNorm + ReLU -> h2 (8 threads/node) ==============
__global__ __launch_bounds__(256) void k_agg1(const float* __restrict__ t1,
                                              const int* __restrict__ row,
                                              const int* __restrict__ adj,
                                              const float* __restrict__ dinvA,
                                              const float* __restrict__ b1,
                                              const float* __restrict__ gma,
                                              const float* __restrict__ bta,
                                              float* __restrict__ h2) {
    int gid = blockIdx.x * 256 + threadIdx.x;
    int n = gid >> 3, f = gid & 7;
    if (n >= NN) return;
    int beg = row[n], end = row[n + 1];
    float dv = dinvA[n];
    float acc = t1[(size_t)n * HH + f] * dv;
    int i = beg;
    for (; i + 4 <= end; i += 4) {                    // unroll-4: more MLP/wave
        int s0 = adj[i], s1 = adj[i + 1], s2 = adj[i + 2], s3 = adj[i + 3];
        float w0 = dinvA[s0], w1 = dinvA[s1], w2 = dinvA[s2], w3 = dinvA[s3];
        float v0 = t1[(size_t)s0 * HH + f], v1 = t1[(size_t)s1 * HH + f];
        float v2 = t1[(size_t)s2 * HH + f], v3 = t1[(size_t)s3 * HH + f];
        acc += v0 * w0 + v1 * w1 + v2 * w2 + v3 * w3;
    }
    for (; i < end; ++i) {
        int s0 = adj[i];
        acc += t1[(size_t)s0 * HH + f] * dinvA[s0];
    }
    acc = acc * dv + b1[f];
    float s = acc;
    s += __shfl_xor(s, 1); s += __shfl_xor(s, 2); s += __shfl_xor(s, 4);
    float mu = s * 0.125f;
    float dx = acc - mu;
    float sq = dx * dx;
    sq += __shfl_xor(sq, 1); sq += __shfl_xor(sq, 2); sq += __shfl_xor(sq, 4);
    float rs = rsqrtf(sq * 0.125f + 1e-5f);
    h2[(size_t)n * HH + f] = fmaxf(dx * rs * gma[f] + bta[f], 0.f);
}

// ===== K6: agg2 (phase A -> LDS) + gemm2 (phase B) ============================
__global__ __launch_bounds__(256) void k_agg2_gemm2(const float* __restrict__ h2,
                                                    const int* __restrict__ row,
                                                    const int* __restrict__ adj,
                                                    const float* __restrict__ dinvA,
                                                    const float* __restrict__ W2,
                                                    const float* __restrict__ b2,
                                                    const float* __restrict__ sf,
                                                    float* __restrict__ out) {
    __shared__ float sA[32 * 8];
    int tid = threadIdx.x;
    int c = tid & 63, g = tid >> 6, d0 = c * 8;
    float w[8][8];
#pragma unroll
    for (int k = 0; k < 8; ++k) {
        float4 u0 = *(const float4*)(W2 + k * DD + d0);
        float4 u1 = *(const float4*)(W2 + k * DD + d0 + 4);
        w[k][0] = u0.x; w[k][1] = u0.y; w[k][2] = u0.z; w[k][3] = u0.w;
        w[k][4] = u1.x; w[k][5] = u1.y; w[k][6] = u1.z; w[k][7] = u1.w;
    }
    float bb[8];
    {
        float4 u0 = *(const float4*)(b2 + d0);
        float4 u1 = *(const float4*)(b2 + d0 + 4);
        bb[0] = u0.x; bb[1] = u0.y; bb[2] = u0.z; bb[3] = u0.w;
        bb[4] = u1.x; bb[5] = u1.y; bb[6] = u1.z; bb[7] = u1.w;
    }
    // ---- phase A: agg2 for 32 nodes ----
    int nl = tid >> 3, f = tid & 7;
    int n = blockIdx.x * 32 + nl;
    if (n < NN) {
        int beg = row[n], end = row[n + 1];
        float dv = dinvA[n];
        float acc = h2[(size_t)n * HH + f] * dv;
        int i = beg;
        for (; i + 4 <= end; i += 4) {                // unroll-4: more MLP/wave
            int s0 = adj[i], s1 = adj[i + 1], s2 = adj[i + 2], s3 = adj[i + 3];
            float w0 = dinvA[s0], w1 = dinvA[s1], w2 = dinvA[s2], w3 = dinvA[s3];
            float v0 = h2[(size_t)s0 * HH + f], v1 = h2[(size_t)s1 * HH + f];
            float v2 = h2[(size_t)s2 * HH + f], v3 = h2[(size_t)s3 * HH + f];
            acc += v0 * w0 + v1 * w1 + v2 * w2 + v3 * w3;
        }
        for (; i < end; ++i) {
            int s0 = adj[i];
            acc += h2[(size_t)s0 * HH + f] * dinvA[s0];
        }
        sA[nl * 8 + f] = acc * dv;
    }
    __syncthreads();
    // ---- phase B: out = relu(agg2 @ W2 + b2) * sf ----
#pragma unroll
    for (int i = 0; i < 8; ++i) {
        int rrow = i * 4 + g;
        int n2 = blockIdx.x * 32 + rrow;
        if (n2 < NN) {
            float a[8];
#pragma unroll
            for (int j = 0; j < 8; ++j) a[j] = sA[rrow * 8 + j];
            float s = sf[n2];
            float acc[8];
#pragma unroll
            for (int j = 0; j < 8; ++j) acc[j] = bb[j];
#pragma unroll
            for (int k = 0; k < 8; ++k)
#pragma unroll
                for (int j = 0; j < 8; ++j) acc[j] += a[k] * w[k][j];
            float4 o0 = make_float4(fmaxf(acc[0], 0.f) * s, fmaxf(acc[1], 0.f) * s,
                                    fmaxf(acc[2], 0.f) * s, fmaxf(acc[3], 0.f) * s);
            float4 o1 = make_float4(fmaxf(acc[4], 0.f) * s, fmaxf(acc[5], 0.f) * s,
                                    fmaxf(acc[6], 0.f) * s, fmaxf(acc[7], 0.f) * s);
            float4* op = (float4*)(out + (size_t)n2 * DD + d0);
            op[0] = o0;
            op[1] = o1;
        }
    }
}

extern "C" void kernel_launch(void* const* d_in, const int* in_sizes, int n_in,
                              void* d_out, int out_size, void* d_ws, size_t ws_size,
                              hipStream_t stream) {
    (void)in_sizes; (void)n_in; (void)out_size; (void)ws_size;
    const float* x   = (const float*)d_in[0];
    const float* sf  = (const float*)d_in[1];
    const float* W1  = (const float*)d_in[2];
    const float* b1  = (const float*)d_in[3];
    const float* gma = (const float*)d_in[4];
    const float* bta = (const float*)d_in[5];
    const float* W2  = (const float*)d_in[6];
    const float* b2  = (const float*)d_in[7];
    const int* eidx  = (const int*)d_in[8];
    float* out = (float*)d_out;

    char* ws = (char*)d_ws;
    int*   blockhist = (int*)(ws + 0);                 // BA*256 ints = 160 KB
    int*   binBase   = (int*)(ws + 262144);            // 257 ints
    int*   binTotal  = (int*)(ws + 262144 + 2048);     // 256 ints
    int*   bar       = (int*)(ws + 262144 + 4096);     // 4 barrier counters
    int*   row       = (int*)(ws + (1 << 20));         // NN+1 ints
    float* dinvA     = (float*)(ws + 2 * (1 << 20));   // NN f32
    float* t1        = (float*)(ws + 3 * (1 << 20));   // NN*8 f32 (1.6 MB)
    float* h2        = (float*)(ws + 5 * (1 << 20));   // NN*8 f32
    int*   adj       = (int*)(ws + 7 * (1 << 20));     // EE ints (3.2 MB)
    int*   bucket    = (int*)(ws + 11 * (1 << 20));    // EE ints (3.2 MB)

    hipMemsetAsync(bar, 0, 16, stream);                // zero barrier counters
    k_mega<<<GOFF + GBLK, 256, 0, stream>>>((const float4*)x, W1, eidx, t1,
                                            blockhist, binTotal, binBase,
                                            bucket, row, adj, dinvA, bar);
    k_agg1<<<AGBLK, 256, 0, stream>>>(t1, row, adj, dinvA, b1, gma, bta, h2);
    k_agg2_gemm2<<<AGBLK, 256, 0, stream>>>(h2, row, adj, dinvA, W2, b2, sf, out);
}

// Round 3
// 270.922 us; speedup vs baseline: 1.3866x; 1.3866x over previous
//
#include <hip/hip_runtime.h>

#define NN 50000
#define EE 800000
#define DD 512
#define HH 8
#define BA 160            // binning blocks (CHUNK = EE/BA exactly)
#define CHUNK 5000
#define NBIN 196          // coarse bins: dst >> 8
#define BCAP 4608         // per-bin edge capacity (mean 4096, sd 64; P(exceed) ~ 1e-13)
#define GBLK 782          // gemm1 tile blocks (4 tiles each)
#define NTILE 3125        // NN/16 exact
#define AGBLK 1563        // ceil(NN*8/256)
#define SCANT 192         // threads for per-bin scan over BA=160 blocks

typedef short bf16x8 __attribute__((ext_vector_type(8)));
typedef float f32x4 __attribute__((ext_vector_type(4)));

union U16 { uint4 u; bf16x8 v; unsigned short h[8]; };

__device__ __forceinline__ unsigned short f2bf(float f) {
    union { float f; unsigned int i; } c; c.f = f;
    unsigned int i = c.i;
    i += 0x7fffu + ((i >> 16) & 1u);   // RNE
    return (unsigned short)(i >> 16);
}

// ===== K1: gemm1 (blocks 0..GBLK-1, 16KB LDS, pipelined loads) || hist ========
__global__ __launch_bounds__(256) void k_gemm1_hist(const float4* __restrict__ x4,
                                                    const float* __restrict__ W1,
                                                    const int* __restrict__ dst,
                                                    float* __restrict__ t1,
                                                    int* __restrict__ blockhist) {
    __shared__ int smem[4096];                        // 16 KB dual-use
    int t = threadIdx.x;
    if (blockIdx.x >= GBLK) {
        // ---------------- histogram path ----------------
        int blk = blockIdx.x - GBLK;
        int* h = smem;
        h[t] = 0; __syncthreads();
        int base = blk * CHUNK;
#pragma unroll
        for (int it = 0; it < 20; ++it) {
            int i = it * 256 + t;
            if (i < CHUNK) atomicAdd(&h[dst[base + i] >> 8], 1);
        }
        __syncthreads();
        blockhist[blk * 256 + t] = h[t];
        return;
    }
    // ---------------- gemm1 path ----------------
    unsigned short* sbf = (unsigned short*)smem;      // 16 KB: [step][lane][j]
    for (int i = t; i < 16 * 64 * 8; i += 256) {
        int lane = (i >> 3) & 63, j = i & 7;
        int n = lane & 15;
        int k = (i >> 9) * 32 + ((lane >> 4) * 8) + j;
        sbf[i] = (n < HH) ? f2bf(W1[k * HH + n]) : (unsigned short)0;
    }
    __syncthreads();
    int wave = t >> 6, lane = t & 63;
    int tile = blockIdx.x * 4 + wave;
    if (tile >= NTILE) return;
    int node0 = tile * 16;
    int m = lane & 15, q = lane >> 4;
    const float4* xrow = x4 + (size_t)(node0 + m) * (DD / 4) + q * 2;
    const uint4* bfrag = (const uint4*)sbf;
    f32x4 acc = {0.f, 0.f, 0.f, 0.f};

    float4 bufA[8], bufB[8];
#define LOADG(buf, g)                                                      \
    _Pragma("unroll")                                                      \
    for (int s = 0; s < 4; ++s) {                                          \
        buf[2 * s]     = xrow[((g) * 4 + s) * 8];                          \
        buf[2 * s + 1] = xrow[((g) * 4 + s) * 8 + 1];                      \
    }
#define MFMAG(buf, g)                                                      \
    _Pragma("unroll")                                                      \
    for (int s = 0; s < 4; ++s) {                                          \
        U16 a, b;                                                          \
        float4 u0 = buf[2 * s], u1 = buf[2 * s + 1];                       \
        a.h[0] = f2bf(u0.x); a.h[1] = f2bf(u0.y);                          \
        a.h[2] = f2bf(u0.z); a.h[3] = f2bf(u0.w);                          \
        a.h[4] = f2bf(u1.x); a.h[5] = f2bf(u1.y);                          \
        a.h[6] = f2bf(u1.z); a.h[7] = f2bf(u1.w);                          \
        b.u = bfrag[((g) * 4 + s) * 64 + lane];                            \
        acc = __builtin_amdgcn_mfma_f32_16x16x32_bf16(a.v, b.v, acc, 0, 0, 0); \
    }
    LOADG(bufA, 0)
    LOADG(bufB, 1)
    MFMAG(bufA, 0)
    LOADG(bufA, 2)
    MFMAG(bufB, 1)
    LOADG(bufB, 3)
    MFMAG(bufA, 2)
    MFMAG(bufB, 3)
#undef LOADG
#undef MFMAG
    if (m < HH) {                                      // C: col=lane&15, row=q*4+r
        int base = (node0 + q * 4) * HH + m;
        t1[base]          = acc[0];
        t1[base + HH]     = acc[1];
        t1[base + 2 * HH] = acc[2];
        t1[base + 3 * HH] = acc[3];
    }
}

// ===== K2a: per-bin parallel scan over the BA block counts (in-place) =========
__global__ __launch_bounds__(SCANT) void k_scan_a(int* __restrict__ blockhist,
                                                  int* __restrict__ binTotal) {
    __shared__ int s[SCANT];
    int bin = blockIdx.x, t = threadIdx.x;
    int v = (t < BA) ? blockhist[t * 256 + bin] : 0;
    s[t] = v; __syncthreads();
    for (int off = 1; off < SCANT; off <<= 1) {
        int x = (t >= off) ? s[t - off] : 0;
        __syncthreads();
        if (t >= off) s[t] += x;
        __syncthreads();
    }
    if (t < BA) blockhist[t * 256 + bin] = s[t] - v;   // bin-local exclusive
    if (t == SCANT - 1) binTotal[bin] = s[t];          // total edges in bin
}

// ===== K2b: tiny cross-bin scan -> binBase ====================================
__global__ __launch_bounds__(256) void k_scan_b(const int* __restrict__ binTotal,
                                                int* __restrict__ binBase,
                                                int* __restrict__ row) {
    __shared__ int s[256];
    int t = threadIdx.x;
    int v = binTotal[t];
    s[t] = v; __syncthreads();
    for (int off = 1; off < 256; off <<= 1) {
        int x = (t >= off) ? s[t - off] : 0;
        __syncthreads();
        if (t >= off) s[t] += x;
        __syncthreads();
    }
    binBase[t] = s[t] - v;
    if (t == 255) { binBase[256] = s[255]; row[NN] = s[255]; }
}

// ===== K3: scatter edges into coarse buckets; packed (src<<8)|dst_local =======
__global__ __launch_bounds__(256) void k_scatter(const int* __restrict__ eidx,
                                                 const int* __restrict__ blockhist,
                                                 const int* __restrict__ binBase,
                                                 int* __restrict__ bucket) {
    __shared__ int cur[256];
    int t = threadIdx.x, blk = blockIdx.x;
    cur[t] = binBase[t] + blockhist[blk * 256 + t]; __syncthreads();
    int base = blk * CHUNK;
#pragma unroll
    for (int it = 0; it < 20; ++it) {
        int i = it * 256 + t;
        if (i < CHUNK) {
            int s = eidx[base + i], d = eidx[EE + base + i];
            int pos = atomicAdd(&cur[d >> 8], 1);
            bucket[pos] = (s << 8) | (d & 255);
        }
    }
}

// ===== K4: build CSR per bin + PRE-SCALE t1 by dinvA (fold norm into feats) ===
__global__ __launch_bounds__(256) void k_build(const int* __restrict__ bucket,
                                               const int* __restrict__ binBase,
                                               int* __restrict__ row,
                                               int* __restrict__ adj,
                                               float* __restrict__ dinvA,
                                               float* __restrict__ t1) {
    __shared__ int smem[2 * BCAP + 768];              // ~39.9 KB
    int t = threadIdx.x;
    int bin = blockIdx.x;
    int n0 = bin << 8;
    int segStart = binBase[bin];
    int count = binBase[bin + 1] - segStart;
    if (count > BCAP) count = BCAP;                   // p ~ 0 guard
    int* lds_in  = smem;                              // packed entries
    int* lds_out = smem + BCAP;
    int* cnt     = smem + 2 * BCAP;
    int* off     = smem + 2 * BCAP + 256;
    int* cur2    = smem + 2 * BCAP + 512;
    cnt[t] = 0; __syncthreads();
    for (int i = t; i < count; i += 256) {
        int p = bucket[segStart + i];
        lds_in[i] = p;
        atomicAdd(&cnt[p & 255], 1);
    }
    __syncthreads();
    off[t] = cnt[t]; __syncthreads();
    for (int o = 1; o < 256; o <<= 1) {
        int x = (t >= o) ? off[t - o] : 0;
        __syncthreads();
        if (t >= o) off[t] += x;
        __syncthreads();
    }
    int excl = off[t] - cnt[t];
    cur2[t] = excl;
    int n = n0 + t;
    if (n < NN) {
        row[n] = segStart + excl;
        float dv = rsqrtf((float)cnt[t] + 1.0f);
        dinvA[n] = dv;
        float4* tp = (float4*)(t1 + (size_t)n * HH);  // t1' = t1 * dinv[n]
        float4 a = tp[0], b = tp[1];
        a.x *= dv; a.y *= dv; a.z *= dv; a.w *= dv;
        b.x *= dv; b.y *= dv; b.z *= dv; b.w *= dv;
        tp[0] = a; tp[1] = b;
    }
    __syncthreads();
    for (int i = t; i < count; i += 256) {
        int p = lds_in[i];
        int pos = atomicAdd(&cur2[p & 255], 1);
        lds_out[pos] = p >> 8;                        // src
    }
    __syncthreads();
    for (int i = t; i < count; i += 256)
        adj[segStart + i] = lds_out[i];               // coalesced stream-out
}

// ===== K5: agg1 + bias + LayerNorm + ReLU -> h2' (pre-scaled by dinv) =========
// t1 is pre-scaled: acc = t1'[n] + sum t1'[s]; out-of-loop: *dv + b1 -> LN.
// No per-edge dinvA gathers; adj read as int4 (4 edges / load instr).
__global__ __launch_bounds__(256) void k_agg1(const float* __restrict__ t1,
                                              const int* __restrict__ row,
                                              const int* __restrict__ adj,
                                              const float* __restrict__ dinvA,
                                              const float* __restrict__ b1,
                                              const float* __restrict__ gma,
                                              const float* __restrict__ bta,
                                              float* __restrict__ h2) {
    int gid = blockIdx.x * 256 + threadIdx.x;
    int n = gid >> 3, f = gid & 7;
    if (n >= NN) return;
    int beg = row[n], end = row[n + 1];
    float dv = dinvA[n];
    float acc = t1[(size_t)n * HH + f];               // self, already *dv
    int i = beg;
    for (; i < end && (i & 3); ++i)                   // align to 16B
        acc += t1[(size_t)adj[i] * HH + f];
    const int4* a4 = (const int4*)adj;
    for (; i + 8 <= end; i += 8) {
        int4 e0 = a4[i >> 2], e1 = a4[(i >> 2) + 1];
        float v0 = t1[(size_t)e0.x * HH + f], v1 = t1[(size_t)e0.y * HH + f];
        float v2 = t1[(size_t)e0.z * HH + f], v3 = t1[(size_t)e0.w * HH + f];
        float v4 = t1[(size_t)e1.x * HH + f], v5 = t1[(size_t)e1.y * HH + f];
        float v6 = t1[(size_t)e1.z * HH + f], v7 = t1[(size_t)e1.w * HH + f];
        acc += ((v0 + v1) + (v2 + v3)) + ((v4 + v5) + (v6 + v7));
    }
    if (i + 4 <= end) {
        int4 e0 = a4[i >> 2];
        float v0 = t1[(size_t)e0.x * HH + f], v1 = t1[(size_t)e0.y * HH + f];
        float v2 = t1[(size_t)e0.z * HH + f], v3 = t1[(size_t)e0.w * HH + f];
        acc += (v0 + v1) + (v2 + v3);
        i += 4;
    }
    for (; i < end; ++i)
        acc += t1[(size_t)adj[i] * HH + f];
    acc = acc * dv + b1[f];
    float s = acc;
    s += __shfl_xor(s, 1); s += __shfl_xor(s, 2); s += __shfl_xor(s, 4);
    float mu = s * 0.125f;
    float dx = acc - mu;
    float sq = dx * dx;
    sq += __shfl_xor(sq, 1); sq += __shfl_xor(sq, 2); sq += __shfl_xor(sq, 4);
    float rs = rsqrtf(sq * 0.125f + 1e-5f);
    h2[(size_t)n * HH + f] = fmaxf(dx * rs * gma[f] + bta[f], 0.f) * dv;  // h2'
}

// ===== K6: agg2 (phase A -> LDS, h2 pre-scaled) + gemm2 (phase B) =============
__global__ __launch_bounds__(256) void k_agg2_gemm2(const float* __restrict__ h2,
                                                    const int* __restrict__ row,
                                                    const int* __restrict__ adj,
                                                    const float* __restrict__ dinvA,
                                                    const float* __restrict__ W2,
                                                    const float* __restrict__ b2,
                                                    const float* __restrict__ sf,
                                                    float* __restrict__ out) {
    __shared__ float sA[32 * 8];
    int tid = threadIdx.x;
    int c = tid & 63, g = tid >> 6, d0 = c * 8;
    float w[8][8];
#pragma unroll
    for (int k = 0; k < 8; ++k) {
        float4 u0 = *(const float4*)(W2 + k * DD + d0);
        float4 u1 = *(const float4*)(W2 + k * DD + d0 + 4);
        w[k][0] = u0.x; w[k][1] = u0.y; w[k][2] = u0.z; w[k][3] = u0.w;
        w[k][4] = u1.x; w[k][5] = u1.y; w[k][6] = u1.z; w[k][7] = u1.w;
    }
    float bb[8];
    {
        float4 u0 = *(const float4*)(b2 + d0);
        float4 u1 = *(const float4*)(b2 + d0 + 4);
        bb[0] = u0.x; bb[1] = u0.y; bb[2] = u0.z; bb[3] = u0.w;
        bb[4] = u1.x; bb[5] = u1.y; bb[6] = u1.z; bb[7] = u1.w;
    }
    // ---- phase A: agg2 for 32 nodes (h2 is pre-scaled h2') ----
    int nl = tid >> 3, f = tid & 7;
    int n = blockIdx.x * 32 + nl;
    if (n < NN) {
        int beg = row[n], end = row[n + 1];
        float dv = dinvA[n];
        float acc = h2[(size_t)n * HH + f];           // self, already *dv
        int i = beg;
        for (; i < end && (i & 3); ++i)
            acc += h2[(size_t)adj[i] * HH + f];
        const int4* a4 = (const int4*)adj;
        for (; i + 8 <= end; i += 8) {
            int4 e0 = a4[i >> 2], e1 = a4[(i >> 2) + 1];
            float v0 = h2[(size_t)e0.x * HH + f], v1 = h2[(size_t)e0.y * HH + f];
            float v2 = h2[(size_t)e0.z * HH + f], v3 = h2[(size_t)e0.w * HH + f];
            float v4 = h2[(size_t)e1.x * HH + f], v5 = h2[(size_t)e1.y * HH + f];
            float v6 = h2[(size_t)e1.z * HH + f], v7 = h2[(size_t)e1.w * HH + f];
            acc += ((v0 + v1) + (v2 + v3)) + ((v4 + v5) + (v6 + v7));
        }
        if (i + 4 <= end) {
            int4 e0 = a4[i >> 2];
            float v0 = h2[(size_t)e0.x * HH + f], v1 = h2[(size_t)e0.y * HH + f];
            float v2 = h2[(size_t)e0.z * HH + f], v3 = h2[(size_t)e0.w * HH + f];
            acc += (v0 + v1) + (v2 + v3);
            i += 4;
        }
        for (; i < end; ++i)
            acc += h2[(size_t)adj[i] * HH + f];
        sA[nl * 8 + f] = acc * dv;
    }
    __syncthreads();
    // ---- phase B: out = relu(agg2 @ W2 + b2) * sf ----
#pragma unroll
    for (int i = 0; i < 8; ++i) {
        int rrow = i * 4 + g;
        int n2 = blockIdx.x * 32 + rrow;
        if (n2 < NN) {
            float a[8];
#pragma unroll
            for (int j = 0; j < 8; ++j) a[j] = sA[rrow * 8 + j];
            float s = sf[n2];
            float acc[8];
#pragma unroll
            for (int j = 0; j < 8; ++j) acc[j] = bb[j];
#pragma unroll
            for (int k = 0; k < 8; ++k)
#pragma unroll
                for (int j = 0; j < 8; ++j) acc[j] += a[k] * w[k][j];
            float4 o0 = make_float4(fmaxf(acc[0], 0.f) * s, fmaxf(acc[1], 0.f) * s,
                                    fmaxf(acc[2], 0.f) * s, fmaxf(acc[3], 0.f) * s);
            float4 o1 = make_float4(fmaxf(acc[4], 0.f) * s, fmaxf(acc[5], 0.f) * s,
                                    fmaxf(acc[6], 0.f) * s, fmaxf(acc[7], 0.f) * s);
            float4* op = (float4*)(out + (size_t)n2 * DD + d0);
            op[0] = o0;
            op[1] = o1;
        }
    }
}

extern "C" void kernel_launch(void* const* d_in, const int* in_sizes, int n_in,
                              void* d_out, int out_size, void* d_ws, size_t ws_size,
                              hipStream_t stream) {
    (void)in_sizes; (void)n_in; (void)out_size; (void)ws_size;
    const float* x   = (const float*)d_in[0];
    const float* sf  = (const float*)d_in[1];
    const float* W1  = (const float*)d_in[2];
    const float* b1  = (const float*)d_in[3];
    const float* gma = (const float*)d_in[4];
    const float* bta = (const float*)d_in[5];
    const float* W2  = (const float*)d_in[6];
    const float* b2  = (const float*)d_in[7];
    const int* eidx  = (const int*)d_in[8];
    float* out = (float*)d_out;

    char* ws = (char*)d_ws;
    int*   blockhist = (int*)(ws + 0);                 // BA*256 ints = 160 KB
    int*   binBase   = (int*)(ws + 262144);            // 257 ints
    int*   binTotal  = (int*)(ws + 262144 + 2048);     // 256 ints
    int*   row       = (int*)(ws + (1 << 20));         // NN+1 ints
    float* dinvA     = (float*)(ws + 2 * (1 << 20));   // NN f32
    float* t1        = (float*)(ws + 3 * (1 << 20));   // NN*8 f32 (1.6 MB)
    float* h2        = (float*)(ws + 5 * (1 << 20));   // NN*8 f32
    int*   adj       = (int*)(ws + 7 * (1 << 20));     // EE ints (3.2 MB)
    int*   bucket    = (int*)(ws + 11 * (1 << 20));    // EE ints (3.2 MB)

    k_gemm1_hist<<<GBLK + BA, 256, 0, stream>>>((const float4*)x, W1, eidx + EE,
                                                t1, blockhist);
    k_scan_a<<<256, SCANT, 0, stream>>>(blockhist, binTotal);
    k_scan_b<<<1, 256, 0, stream>>>(binTotal, binBase, row);
    k_scatter<<<BA, 256, 0, stream>>>(eidx, blockhist, binBase, bucket);
    k_build<<<NBIN, 256, 0, stream>>>(bucket, binBase, row, adj, dinvA, t1);
    k_agg1<<<AGBLK, 256, 0, stream>>>(t1, row, adj, dinvA, b1, gma, bta, h2);
    k_agg2_gemm2<<<AGBLK, 256, 0, stream>>>(h2, row, adj, dinvA, W2, b2, sf, out);
}